// Round 7
// baseline (2636.064 us; speedup 1.0000x reference)
//
#include <hip/hip_runtime.h>
#include <hip/hip_bf16.h>

// LSTM: B=64, T=512, V=32000, E=256, H=512, O=1
// R7: two-phase. Phase 1 precomputes xg[t][col][b] = emb[words]·Wi + bi + bh
// (bf16, in d_ws) with a parallel MFMA GEMM. Phase 2 is the persistent
// recurrence kernel (R5 geometry: 4 sync domains x 16 blocks x 256 thr),
// tagged 8-byte-atomic h exchange (no flags/fences/RMW), with the serial
// loop stripped to: poll -> h->LDS -> MFMA -> act -> publish.
// If ws_size can't hold xg, falls back to the proven R5 kernel.
#define TB 512
#define NB 64
#define EE 256
#define HH 512
#define NG 4          // batch groups (sync domains)
#define GB 16         // batches per group
#define NT 256        // threads per block (4 waves)
#define NCOLP 132     // P_lds padded row
#define NPAIR 256     // h pairs per batch
#define GCOLS 2048    // total gate columns
#define XGOFF ((size_t)1 << 20)   // xg offset inside d_ws

typedef __bf16 bf16_t;
typedef bf16_t bf16x8 __attribute__((ext_vector_type(8)));
typedef float  f32x4  __attribute__((ext_vector_type(4)));
typedef unsigned long long u64;
typedef unsigned u32;

__device__ __forceinline__ float sigf(float x) { return 1.0f / (1.0f + __expf(-x)); }
__device__ __forceinline__ float tanhfast(float x) {
    float xc = fminf(fmaxf(x, -15.0f), 15.0f);
    float e  = __expf(2.0f * xc);
    return (e - 1.0f) / (e + 1.0f);
}
__device__ __forceinline__ unsigned bfbits(float f) {
    bf16_t h = (bf16_t)f;
    return (unsigned)__builtin_bit_cast(unsigned short, h);
}
__device__ __forceinline__ bf16x8 cvt8(float4 a, float4 b) {
    bf16x8 v;
    v[0]=(bf16_t)a.x; v[1]=(bf16_t)a.y; v[2]=(bf16_t)a.z; v[3]=(bf16_t)a.w;
    v[4]=(bf16_t)b.x; v[5]=(bf16_t)b.y; v[6]=(bf16_t)b.z; v[7]=(bf16_t)b.w;
    return v;
}
__device__ __forceinline__ f32x4 cvtxg(u64 v) {
    f32x4 r;
    r[0] = __uint_as_float((u32)( v        & 0xFFFFu) << 16);
    r[1] = __uint_as_float((u32)((v >> 16) & 0xFFFFu) << 16);
    r[2] = __uint_as_float((u32)((v >> 32) & 0xFFFFu) << 16);
    r[3] = __uint_as_float((u32)((v >> 48) & 0xFFFFu) << 16);
    return r;
}

// ---------------- Phase 1: xg pre-pass GEMM ----------------
// grid 256: cc = blockIdx&7 (256-col chunk), tc = blockIdx>>3 (16-t chunk)
__global__ __launch_bounds__(256, 1)
void xg_prepass(const int* __restrict__ words, const float* __restrict__ emb,
                const float* __restrict__ Wi, const float* __restrict__ bi,
                const float* __restrict__ bh, bf16_t* __restrict__ xgT)
{
    const int tid = threadIdx.x, lane = tid & 63, wv = tid >> 6;
    const int kgrp = lane >> 4, cl = lane & 15;
    const int cc = blockIdx.x & 7, tc = blockIdx.x >> 3;

    __shared__ __align__(16) bf16_t x_s[64][EE];   // 32 KiB

    // Wi fragments + folded bias for this block's 256 cols
    bf16x8 wf[8][4];
    float  bv[4];
    #pragma unroll
    for (int nt = 0; nt < 4; ++nt) {
        int col = cc*256 + wv*64 + nt*16 + cl;
        int ug = col >> 7, l = col & 127, ul = l >> 2, g = l & 3;
        int wrow = g*HH + ug*32 + ul;
        const float* wr = Wi + (size_t)wrow*EE;
        #pragma unroll
        for (int kt = 0; kt < 8; ++kt) {
            const float4* p = (const float4*)(wr + kt*32 + kgrp*8);
            wf[kt][nt] = cvt8(p[0], p[1]);
        }
        bv[nt] = bi[wrow] + bh[wrow];
    }

    const int r0 = tid >> 2, q = tid & 3;          // stage: batch row r0, quarter q
    const int swz = (r0 & 7) << 3;
    u64* dst = (u64*)xgT;

    for (int it = 0; it < 16; ++it) {
        int t = tc*16 + it;
        {
            int wd = words[r0*TB + t];
            const float4* p = (const float4*)(emb + (size_t)wd*EE + q*64);
            #pragma unroll
            for (int o = 0; o < 8; ++o) {
                float4 a = p[2*o], b2 = p[2*o + 1];
                *(bf16x8*)&x_s[r0][(q*64 + o*8) ^ swz] = cvt8(a, b2);
            }
        }
        __syncthreads();

        f32x4 acc[4][4];
        #pragma unroll
        for (int rt = 0; rt < 4; ++rt)
            #pragma unroll
            for (int nt = 0; nt < 4; ++nt)
                acc[rt][nt] = (f32x4){ bv[nt], bv[nt], bv[nt], bv[nt] };
        #pragma unroll
        for (int kt = 0; kt < 8; ++kt) {
            #pragma unroll
            for (int rt = 0; rt < 4; ++rt) {
                bf16x8 a = *(const bf16x8*)&x_s[rt*16 + cl][(kt*32 + kgrp*8) ^ ((cl & 7) << 3)];
                #pragma unroll
                for (int nt = 0; nt < 4; ++nt)
                    acc[rt][nt] = __builtin_amdgcn_mfma_f32_16x16x32_bf16(a, wf[kt][nt], acc[rt][nt], 0, 0, 0);
            }
        }
        // store: xgT[t][col][batch], 4 bf16 (batches rt*16+kgrp*4 .. +3) per u64
        #pragma unroll
        for (int nt = 0; nt < 4; ++nt) {
            int col = cc*256 + wv*64 + nt*16 + cl;
            #pragma unroll
            for (int rt = 0; rt < 4; ++rt) {
                f32x4 v = acc[rt][nt];
                u64 pk =  (u64)(bfbits(v[0]))
                       | ((u64)(bfbits(v[1])) << 16)
                       | ((u64)(bfbits(v[2])) << 32)
                       | ((u64)(bfbits(v[3])) << 48);
                dst[(size_t)(t*GCOLS + col)*16 + rt*4 + kgrp] = pk;
            }
        }
        __syncthreads();
    }
}

// ---------------- Phase 2: persistent recurrence ----------------
__global__ __launch_bounds__(NT, 1)
void lstm_main(const float* __restrict__ Wh,
               const float* __restrict__ Wfc,
               const float* __restrict__ bfc,
               float* __restrict__ out,        // [64] head + [64*512] h (fp32)
               u64* __restrict__ tagH,         // [2][NB][NPAIR] tagged pairs
               const u64* __restrict__ xg64)   // xg[t][col][b] as u64 quads
{
    const int tid  = threadIdx.x;
    const int lane = tid & 63;
    const int wv   = tid >> 6;        // 0..3
    const int bg   = blockIdx.x & 3;  // batch group / sync domain
    const int ug   = blockIdx.x >> 2; // unit group 0..15
    const int kgrp = lane >> 4;       // k-octet selector 0..3
    const int cl   = lane & 15;       // A row / B col within 16x16 tile

    __shared__ __align__(16) bf16_t h_lds[16][HH];    // 16 KiB
    __shared__ __align__(16) float  P_lds[16][NCOLP]; // 8.25 KiB

    // ---- Wh fragments, stationary for all 512 steps ----
    bf16x8 whf[16][2];
    #pragma unroll
    for (int nt = 0; nt < 2; ++nt) {
        int col = wv*32 + nt*16 + cl;         // 0..127
        int ul  = col >> 2, g = col & 3;
        int row = g*HH + ug*32 + ul;
        const float* wr = Wh + (size_t)row*HH;
        #pragma unroll
        for (int kt = 0; kt < 16; ++kt) {
            const float4* p = (const float4*)(wr + kt*32 + kgrp*8);
            whf[kt][nt] = cvt8(p[0], p[1]);
        }
    }

    const int sb = tid & 15, sc = tid >> 4;
    const int swz = (sb & 7) << 3;
    const int gcol0 = ug*128 + wv*32 + cl, gcol1 = gcol0 + 16;
    const size_t xoff = (size_t)bg*4 + kgrp;     // u64 offset within a col

    u64 xgc0 = xg64[(size_t)gcol0*16 + xoff];    // xg(0)
    u64 xgc1 = xg64[(size_t)gcol1*16 + xoff];
    u64 xgn0 = 0, xgn1 = 0;

    float c0 = 0.f, c1 = 0.f;

    for (int t = 0; t < TB; ++t) {
        // ---- poll tagged h_{t-1}: thread (sb,sc) owns producer sc's 16 pairs ----
        if (t > 0) {
            const u64* src = tagH + ((size_t)((t & 1) ^ 1))*NB*NPAIR
                                  + (size_t)(bg*GB + sb)*NPAIR + sc*16;
            const u32 tag = (u32)t;
            u64 hv[16];
            for (;;) {
                #pragma unroll
                for (int j = 0; j < 16; ++j)
                    hv[j] = __hip_atomic_load(src + j, __ATOMIC_RELAXED, __HIP_MEMORY_SCOPE_AGENT);
                bool ok = true;
                #pragma unroll
                for (int j = 0; j < 16; ++j) ok &= ((u32)(hv[j] >> 32) == tag);
                if (ok) break;
                __builtin_amdgcn_s_sleep(1);
            }
            #pragma unroll
            for (int j = 0; j < 16; j += 2) {
                u64 pk = (u64)(u32)hv[j] | ((u64)(u32)hv[j+1] << 32);
                int elem = sc*32 + 2*j;
                int phys = ((elem & ~7) ^ swz) | (elem & 7);
                *(u64*)&h_lds[sb][phys] = pk;
            }
        }

        // ---- prefetch xg(t+1): sequential, one full step of slack ----
        if (t + 1 < TB) {
            xgn0 = xg64[(size_t)((t + 1)*GCOLS + gcol0)*16 + xoff];
            xgn1 = xg64[(size_t)((t + 1)*GCOLS + gcol1)*16 + xoff];
        }
        __syncthreads();   // B1: h_lds visible

        // ---- recurrent MFMAs; acc seeded with xg_t (bias pre-folded) ----
        f32x4 acc0 = cvtxg(xgc0);
        f32x4 acc1 = cvtxg(xgc1);
        if (t > 0) {
            #pragma unroll
            for (int kt = 0; kt < 16; ++kt) {
                bf16x8 a = *(const bf16x8*)&h_lds[cl][(kt*32 + kgrp*8) ^ ((cl & 7) << 3)];
                acc0 = __builtin_amdgcn_mfma_f32_16x16x32_bf16(a, whf[kt][0], acc0, 0, 0, 0);
                acc1 = __builtin_amdgcn_mfma_f32_16x16x32_bf16(a, whf[kt][1], acc1, 0, 0, 0);
            }
        }

        // ---- preactivations to LDS: D row=(kgrp*4+r)=batch, col=cl ----
        #pragma unroll
        for (int r = 0; r < 4; ++r) {
            P_lds[kgrp*4 + r][wv*32 + cl]      = acc0[r];
            P_lds[kgrp*4 + r][wv*32 + 16 + cl] = acc1[r];
        }
        __syncthreads();   // B2: P visible

        // ---- activations + cell update: thread owns (b,u) and (b+8,u) ----
        {
            int b = tid >> 5, u = tid & 31;
            float4 g0 = *(const float4*)&P_lds[b][u*4];
            float4 g1 = *(const float4*)&P_lds[b + 8][u*4];
            float r0 = sigf(g0.x), f0 = sigf(g0.y), z0 = tanhfast(g0.z), o0 = sigf(g0.w);
            float r1 = sigf(g1.x), f1 = sigf(g1.y), z1 = tanhfast(g1.z), o1 = sigf(g1.w);
            c0 = f0*c0 + r0*z0;
            c1 = f1*c1 + r1*z1;
            float h0 = o0*tanhfast(c0);
            float h1 = o1*tanhfast(c1);
            if (t == TB - 1) {
                out[64 + (size_t)(bg*GB + b    )*HH + ug*32 + u] = h0;
                out[64 + (size_t)(bg*GB + b + 8)*HH + ug*32 + u] = h1;
            }
            unsigned s0 = bfbits(h0), s1 = bfbits(h1);
            unsigned n0 = (unsigned)__shfl_down((int)s0, 1);
            unsigned n1 = (unsigned)__shfl_down((int)s1, 1);
            if (!(u & 1)) {
                u64 tg = ((u64)(u32)(t + 1)) << 32;
                u64 v0 = tg | (u64)((s0 & 0xFFFFu) | (n0 << 16));
                u64 v1 = tg | (u64)((s1 & 0xFFFFu) | (n1 << 16));
                size_t base = ((size_t)(t & 1))*NB*NPAIR;
                size_t p0 = base + (size_t)(bg*GB + b    )*NPAIR + ug*16 + (u >> 1);
                size_t p1 = base + (size_t)(bg*GB + b + 8)*NPAIR + ug*16 + (u >> 1);
                __hip_atomic_store(tagH + p0, v0, __ATOMIC_RELAXED, __HIP_MEMORY_SCOPE_AGENT);
                __hip_atomic_store(tagH + p1, v1, __ATOMIC_RELAXED, __HIP_MEMORY_SCOPE_AGENT);
            }
        }
        xgc0 = xgn0; xgc1 = xgn1;
        // no end-of-step barrier, no flag, no fence
    }

    // ---- final FC head: block ug==0 of each group ----
    if (ug == 0) {
        const u64* src = tagH + ((size_t)((TB - 1) & 1))*NB*NPAIR
                              + (size_t)(bg*GB + sb)*NPAIR + sc*16;
        u64 hv[16];
        for (;;) {
            #pragma unroll
            for (int j = 0; j < 16; ++j)
                hv[j] = __hip_atomic_load(src + j, __ATOMIC_RELAXED, __HIP_MEMORY_SCOPE_AGENT);
            bool ok = true;
            #pragma unroll
            for (int j = 0; j < 16; ++j) ok &= ((u32)(hv[j] >> 32) == (u32)TB);
            if (ok) break;
            __builtin_amdgcn_s_sleep(1);
        }
        float s = 0.f;
        #pragma unroll
        for (int j = 0; j < 16; ++j) {
            u32 pl = (u32)hv[j];
            float h0 = __uint_as_float((pl & 0xFFFFu) << 16);
            float h1 = __uint_as_float(pl & 0xFFFF0000u);
            s += h0 * Wfc[sc*32 + 2*j] + h1 * Wfc[sc*32 + 2*j + 1];
        }
        __syncthreads();
        P_lds[sb][sc] = s;
        __syncthreads();
        if (tid < 16) {
            float acc = 0.f;
            #pragma unroll
            for (int q = 0; q < 16; ++q) acc += P_lds[tid][q];
            out[bg*GB + tid] = sigf(acc + bfc[0]);
        }
    }
}

// ---------------- Fallback: proven R5 kernel (used if ws too small) ----------------
__global__ __launch_bounds__(NT, 1)
void lstm_persistent_v5(const int* __restrict__ words,
                        const float* __restrict__ emb,
                        const float* __restrict__ Wi,
                        const float* __restrict__ bi,
                        const float* __restrict__ Wh,
                        const float* __restrict__ bh,
                        const float* __restrict__ Wfc,
                        const float* __restrict__ bfc,
                        float* __restrict__ out,
                        u64* __restrict__ tagH)
{
    const int tid  = threadIdx.x;
    const int lane = tid & 63;
    const int wv   = tid >> 6;
    const int bg   = blockIdx.x & 3;
    const int ug   = blockIdx.x >> 2;
    const int kgrp = lane >> 4;
    const int cl   = lane & 15;

    __shared__ __align__(16) bf16_t h_lds[16][HH];
    __shared__ __align__(16) bf16_t x_lds[2][16][EE];
    __shared__ __align__(16) float  P_lds[16][NCOLP];

    for (int i = tid; i < 16*HH/2; i += NT) ((unsigned*)h_lds)[i] = 0u;

    bf16x8 whf[16][2];
    bf16x8 wif[8][2];
    float  biasn[2];
    #pragma unroll
    for (int nt = 0; nt < 2; ++nt) {
        int col = wv*32 + nt*16 + cl;
        int ul  = col >> 2, g = col & 3;
        int row = g*HH + ug*32 + ul;
        const float* wr = Wh + (size_t)row*HH;
        #pragma unroll
        for (int kt = 0; kt < 16; ++kt) {
            const float4* p = (const float4*)(wr + kt*32 + kgrp*8);
            whf[kt][nt] = cvt8(p[0], p[1]);
        }
        const float* wir = Wi + (size_t)row*EE;
        #pragma unroll
        for (int kt = 0; kt < 8; ++kt) {
            const float4* p = (const float4*)(wir + kt*32 + kgrp*8);
            wif[kt][nt] = cvt8(p[0], p[1]);
        }
        biasn[nt] = bi[row] + bh[row];
    }

    const int sb = tid & 15, sc = tid >> 4;
    const int swz = (sb & 7) << 3;
    {
        int word = words[(bg*GB + sb)*TB + 0];
        const float4* p = (const float4*)(emb + (size_t)word*EE + sc*16);
        float4 a=p[0], b=p[1], c=p[2], d=p[3];
        *(bf16x8*)&x_lds[0][sb][(sc*16    ) ^ swz] = cvt8(a, b);
        *(bf16x8*)&x_lds[0][sb][(sc*16 + 8) ^ swz] = cvt8(c, d);
    }

    float c0 = 0.f, c1 = 0.f;
    __syncthreads();

    for (int t = 0; t < TB; ++t) {
        f32x4 acc0 = { biasn[0], biasn[0], biasn[0], biasn[0] };
        f32x4 acc1 = { biasn[1], biasn[1], biasn[1], biasn[1] };
        const bf16_t (*xl)[EE] = x_lds[t & 1];
        #pragma unroll
        for (int kt = 0; kt < 8; ++kt) {
            bf16x8 a = *(const bf16x8*)&xl[cl][(kt*32 + kgrp*8) ^ ((cl & 7) << 3)];
            acc0 = __builtin_amdgcn_mfma_f32_16x16x32_bf16(a, wif[kt][0], acc0, 0, 0, 0);
            acc1 = __builtin_amdgcn_mfma_f32_16x16x32_bf16(a, wif[kt][1], acc1, 0, 0, 0);
        }
        float4 xa, xb, xc, xd;
        const bool havex = (t + 1 < TB);
        if (havex) {
            int word = words[(bg*GB + sb)*TB + (t + 1)];
            const float4* p = (const float4*)(emb + (size_t)word*EE + sc*16);
            xa = p[0]; xb = p[1]; xc = p[2]; xd = p[3];
        }
        if (t > 0) {
            const u64* src = tagH + ((size_t)((t & 1) ^ 1))*NB*NPAIR
                                  + (size_t)(bg*GB + sb)*NPAIR + sc*16;
            const u32 tag = (u32)t;
            u64 hv[16];
            for (;;) {
                #pragma unroll
                for (int j = 0; j < 16; ++j)
                    hv[j] = __hip_atomic_load(src + j, __ATOMIC_RELAXED, __HIP_MEMORY_SCOPE_AGENT);
                bool ok = true;
                #pragma unroll
                for (int j = 0; j < 16; ++j) ok &= ((u32)(hv[j] >> 32) == tag);
                if (ok) break;
                __builtin_amdgcn_s_sleep(1);
            }
            #pragma unroll
            for (int j = 0; j < 16; j += 2) {
                u64 pk = (u64)(u32)hv[j] | ((u64)(u32)hv[j+1] << 32);
                int elem = sc*32 + 2*j;
                int phys = ((elem & ~7) ^ swz) | (elem & 7);
                *(u64*)&h_lds[sb][phys] = pk;
            }
        }
        if (havex) {
            bf16_t (*xn)[EE] = x_lds[(t + 1) & 1];
            *(bf16x8*)&xn[sb][(sc*16    ) ^ swz] = cvt8(xa, xb);
            *(bf16x8*)&xn[sb][(sc*16 + 8) ^ swz] = cvt8(xc, xd);
        }
        __syncthreads();
        #pragma unroll
        for (int kt = 0; kt < 16; ++kt) {
            bf16x8 a = *(const bf16x8*)&h_lds[cl][(kt*32 + kgrp*8) ^ ((cl & 7) << 3)];
            acc0 = __builtin_amdgcn_mfma_f32_16x16x32_bf16(a, whf[kt][0], acc0, 0, 0, 0);
            acc1 = __builtin_amdgcn_mfma_f32_16x16x32_bf16(a, whf[kt][1], acc1, 0, 0, 0);
        }
        #pragma unroll
        for (int r = 0; r < 4; ++r) {
            P_lds[kgrp*4 + r][wv*32 + cl]      = acc0[r];
            P_lds[kgrp*4 + r][wv*32 + 16 + cl] = acc1[r];
        }
        __syncthreads();
        {
            int b = tid >> 5, u = tid & 31;
            float4 g0 = *(const float4*)&P_lds[b][u*4];
            float4 g1 = *(const float4*)&P_lds[b + 8][u*4];
            float r0 = sigf(g0.x), f0 = sigf(g0.y), z0 = tanhfast(g0.z), o0 = sigf(g0.w);
            float r1 = sigf(g1.x), f1 = sigf(g1.y), z1 = tanhfast(g1.z), o1 = sigf(g1.w);
            c0 = f0*c0 + r0*z0;
            c1 = f1*c1 + r1*z1;
            float h0 = o0*tanhfast(c0);
            float h1 = o1*tanhfast(c1);
            if (t == TB - 1) {
                out[64 + (size_t)(bg*GB + b    )*HH + ug*32 + u] = h0;
                out[64 + (size_t)(bg*GB + b + 8)*HH + ug*32 + u] = h1;
            }
            unsigned s0 = bfbits(h0), s1 = bfbits(h1);
            unsigned n0 = (unsigned)__shfl_down((int)s0, 1);
            unsigned n1 = (unsigned)__shfl_down((int)s1, 1);
            if (!(u & 1)) {
                u64 tg = ((u64)(u32)(t + 1)) << 32;
                u64 v0 = tg | (u64)((s0 & 0xFFFFu) | (n0 << 16));
                u64 v1 = tg | (u64)((s1 & 0xFFFFu) | (n1 << 16));
                size_t base = ((size_t)(t & 1))*NB*NPAIR;
                size_t p0 = base + (size_t)(bg*GB + b    )*NPAIR + ug*16 + (u >> 1);
                size_t p1 = base + (size_t)(bg*GB + b + 8)*NPAIR + ug*16 + (u >> 1);
                __hip_atomic_store(tagH + p0, v0, __ATOMIC_RELAXED, __HIP_MEMORY_SCOPE_AGENT);
                __hip_atomic_store(tagH + p1, v1, __ATOMIC_RELAXED, __HIP_MEMORY_SCOPE_AGENT);
            }
        }
    }
    if (ug == 0) {
        const u64* src = tagH + ((size_t)((TB - 1) & 1))*NB*NPAIR
                              + (size_t)(bg*GB + sb)*NPAIR + sc*16;
        u64 hv[16];
        for (;;) {
            #pragma unroll
            for (int j = 0; j < 16; ++j)
                hv[j] = __hip_atomic_load(src + j, __ATOMIC_RELAXED, __HIP_MEMORY_SCOPE_AGENT);
            bool ok = true;
            #pragma unroll
            for (int j = 0; j < 16; ++j) ok &= ((u32)(hv[j] >> 32) == (u32)TB);
            if (ok) break;
            __builtin_amdgcn_s_sleep(1);
        }
        float s = 0.f;
        #pragma unroll
        for (int j = 0; j < 16; ++j) {
            u32 pl = (u32)hv[j];
            float h0 = __uint_as_float((pl & 0xFFFFu) << 16);
            float h1 = __uint_as_float(pl & 0xFFFF0000u);
            s += h0 * Wfc[sc*32 + 2*j] + h1 * Wfc[sc*32 + 2*j + 1];
        }
        __syncthreads();
        P_lds[sb][sc] = s;
        __syncthreads();
        if (tid < 16) {
            float acc = 0.f;
            #pragma unroll
            for (int q = 0; q < 16; ++q) acc += P_lds[tid][q];
            out[bg*GB + tid] = sigf(acc + bfc[0]);
        }
    }
}

extern "C" void kernel_launch(void* const* d_in, const int* in_sizes, int n_in,
                              void* d_out, int out_size, void* d_ws, size_t ws_size,
                              hipStream_t stream) {
    (void)in_sizes; (void)n_in; (void)out_size;
    const int*   words = (const int*)d_in[0];
    const float* emb   = (const float*)d_in[1];
    const float* Wi    = (const float*)d_in[2];
    const float* bi    = (const float*)d_in[3];
    const float* Wh    = (const float*)d_in[4];
    const float* bh    = (const float*)d_in[5];
    const float* Wfc   = (const float*)d_in[6];
    const float* bfc   = (const float*)d_in[7];
    float* out = (float*)d_out;

    u64* tagH = (u64*)d_ws;
    hipMemsetAsync(d_ws, 0, (size_t)2*NB*NPAIR*sizeof(u64), stream);

    const size_t need = XGOFF + (size_t)TB*GCOLS*NB*sizeof(bf16_t);
    if (ws_size >= need) {
        bf16_t* xgT = (bf16_t*)((char*)d_ws + XGOFF);
        xg_prepass<<<dim3(256), dim3(256), 0, stream>>>(words, emb, Wi, bi, bh, xgT);
        lstm_main<<<dim3(NG*GB), dim3(NT), 0, stream>>>(Wh, Wfc, bfc, out, tagH, (const u64*)xgT);
    } else {
        lstm_persistent_v5<<<dim3(NG*GB), dim3(NT), 0, stream>>>(
            words, emb, Wi, bi, Wh, bh, Wfc, bfc, out, tagH);
    }
}

// Round 9
// 2017.014 us; speedup vs baseline: 1.3069x; 1.3069x over previous
//
#include <hip/hip_runtime.h>
#include <hip/hip_bf16.h>

// LSTM: B=64, T=512, V=32000, E=256, H=512, O=1
// R9: xg pre-pass (proven R7) + persistent recurrence with DUAL-PROTOCOL
// tagged exchange: every h-pair u64 (tag<<32 | 2xbf16) is stored BOTH
//   fast: global_store_dwordx2 ... sc0  (L2-visible if consumer on same XCD)
//   slow: agent-scope relaxed atomic    (always MALL-visible; proven R5-R7)
// Consumers hot-spin on the fast buffer, probing the slow buffer every 4th
// iteration. Liveness never depends on XCD placement; speed does.
// 8 domains (8 batches each) x 8 blocks (domain = blockIdx&7 -> one XCD
// under round-robin dispatch) x 256 threads.
#define TB 512
#define NB 64
#define EE 256
#define HH 512
#define ND 8           // sync domains
#define DB 8           // batches per domain
#define NBLK 8         // blocks per domain
#define NT 256         // threads per block (4 waves)
#define NCOLP 260      // P_lds padded row (floats)
#define NPAIR 256      // h pairs per batch
#define GCOLS 2048
#define SLOWOFF ((size_t)0x40000)  // slow buffer offset (fast at 0, 256KB each)
#define XGOFF   ((size_t)1 << 20)  // xg offset in d_ws

typedef __bf16 bf16_t;
typedef bf16_t bf16x8 __attribute__((ext_vector_type(8)));
typedef float  f32x4  __attribute__((ext_vector_type(4)));
typedef unsigned u32;
typedef unsigned long long u64;
typedef u32 u32x4 __attribute__((ext_vector_type(4)));

__device__ __forceinline__ float sigf(float x) { return 1.0f / (1.0f + __expf(-x)); }
__device__ __forceinline__ float tanhfast(float x) {
    float xc = fminf(fmaxf(x, -15.0f), 15.0f);
    float e  = __expf(2.0f * xc);
    return (e - 1.0f) / (e + 1.0f);
}
__device__ __forceinline__ u32 bfbits(float f) {
    bf16_t h = (bf16_t)f;
    return (u32)__builtin_bit_cast(unsigned short, h);
}
__device__ __forceinline__ bf16x8 cvt8(float4 a, float4 b) {
    bf16x8 v;
    v[0]=(bf16_t)a.x; v[1]=(bf16_t)a.y; v[2]=(bf16_t)a.z; v[3]=(bf16_t)a.w;
    v[4]=(bf16_t)b.x; v[5]=(bf16_t)b.y; v[6]=(bf16_t)b.z; v[7]=(bf16_t)b.w;
    return v;
}
__device__ __forceinline__ f32x4 cvtxg(u64 v) {
    f32x4 r;
    r[0] = __uint_as_float((u32)( v        & 0xFFFFu) << 16);
    r[1] = __uint_as_float((u32)((v >> 16) & 0xFFFFu) << 16);
    r[2] = __uint_as_float((u32)((v >> 32) & 0xFFFFu) << 16);
    r[3] = __uint_as_float((u32)((v >> 48) & 0xFFFFu) << 16);
    return r;
}

// Dual poll of 8 tagged u64s (64B): hot-spin sc0 (L2), slow probe every 4th.
// Tags ride in the data words, so acceptance is self-validating; the slow
// probe guarantees termination regardless of XCD placement.
__device__ __forceinline__ void poll8_dual(const u64* fsrc, const u64* ssrc,
                                           u32 tag, u64 (&pk)[4]) {
    u64 fa = (u64)fsrc;
    int it = 0;
    for (;;) {
        u32x4 q0, q1, q2, q3;
        asm volatile(
            "global_load_dwordx4 %0, %4, off sc0\n\t"
            "global_load_dwordx4 %1, %4, off offset:16 sc0\n\t"
            "global_load_dwordx4 %2, %4, off offset:32 sc0\n\t"
            "global_load_dwordx4 %3, %4, off offset:48 sc0\n\t"
            "s_waitcnt vmcnt(0)"
            : "=&v"(q0), "=&v"(q1), "=&v"(q2), "=&v"(q3)
            : "v"(fa)
            : "memory");
        if (q0[1]==tag && q0[3]==tag && q1[1]==tag && q1[3]==tag &&
            q2[1]==tag && q2[3]==tag && q3[1]==tag && q3[3]==tag) {
            pk[0] = (u64)q0[0] | ((u64)q0[2] << 32);
            pk[1] = (u64)q1[0] | ((u64)q1[2] << 32);
            pk[2] = (u64)q2[0] | ((u64)q2[2] << 32);
            pk[3] = (u64)q3[0] | ((u64)q3[2] << 32);
            return;
        }
        if (((++it) & 3) == 0) {
            u64 hv[8];
            #pragma unroll
            for (int j = 0; j < 8; ++j)
                hv[j] = __hip_atomic_load(ssrc + j, __ATOMIC_RELAXED, __HIP_MEMORY_SCOPE_AGENT);
            bool ok = true;
            #pragma unroll
            for (int j = 0; j < 8; ++j) ok &= ((u32)(hv[j] >> 32) == tag);
            if (ok) {
                #pragma unroll
                for (int k = 0; k < 4; ++k)
                    pk[k] = (u64)(u32)hv[2*k] | ((u64)(u32)hv[2*k + 1] << 32);
                return;
            }
        }
    }
}

// ---------------- Phase 1: xg pre-pass GEMM (proven R7, verbatim) ----------------
__global__ __launch_bounds__(256, 1)
void xg_prepass(const int* __restrict__ words, const float* __restrict__ emb,
                const float* __restrict__ Wi, const float* __restrict__ bi,
                const float* __restrict__ bh, bf16_t* __restrict__ xgT)
{
    const int tid = threadIdx.x, lane = tid & 63, wv = tid >> 6;
    const int kgrp = lane >> 4, cl = lane & 15;
    const int cc = blockIdx.x & 7, tc = blockIdx.x >> 3;

    __shared__ __align__(16) bf16_t x_s[64][EE];

    bf16x8 wf[8][4];
    float  bv[4];
    #pragma unroll
    for (int nt = 0; nt < 4; ++nt) {
        int col = cc*256 + wv*64 + nt*16 + cl;
        int wrow = (col & 3)*HH + (col >> 2);
        const float* wr = Wi + (size_t)wrow*EE;
        #pragma unroll
        for (int kt = 0; kt < 8; ++kt) {
            const float4* p = (const float4*)(wr + kt*32 + kgrp*8);
            wf[kt][nt] = cvt8(p[0], p[1]);
        }
        bv[nt] = bi[wrow] + bh[wrow];
    }

    const int r0 = tid >> 2, q = tid & 3;
    const int swz = (r0 & 7) << 3;
    u64* dst = (u64*)xgT;

    for (int it = 0; it < 16; ++it) {
        int t = tc*16 + it;
        {
            int wd = words[r0*TB + t];
            const float4* p = (const float4*)(emb + (size_t)wd*EE + q*64);
            #pragma unroll
            for (int o = 0; o < 8; ++o) {
                float4 a = p[2*o], b2 = p[2*o + 1];
                *(bf16x8*)&x_s[r0][(q*64 + o*8) ^ swz] = cvt8(a, b2);
            }
        }
        __syncthreads();

        f32x4 acc[4][4];
        #pragma unroll
        for (int rt = 0; rt < 4; ++rt)
            #pragma unroll
            for (int nt = 0; nt < 4; ++nt)
                acc[rt][nt] = (f32x4){ bv[nt], bv[nt], bv[nt], bv[nt] };
        #pragma unroll
        for (int kt = 0; kt < 8; ++kt) {
            #pragma unroll
            for (int rt = 0; rt < 4; ++rt) {
                bf16x8 a = *(const bf16x8*)&x_s[rt*16 + cl][(kt*32 + kgrp*8) ^ ((cl & 7) << 3)];
                #pragma unroll
                for (int nt = 0; nt < 4; ++nt)
                    acc[rt][nt] = __builtin_amdgcn_mfma_f32_16x16x32_bf16(a, wf[kt][nt], acc[rt][nt], 0, 0, 0);
            }
        }
        #pragma unroll
        for (int nt = 0; nt < 4; ++nt) {
            int col = cc*256 + wv*64 + nt*16 + cl;
            #pragma unroll
            for (int rt = 0; rt < 4; ++rt) {
                f32x4 v = acc[rt][nt];
                u64 pkk =  (u64)(bfbits(v[0]))
                        | ((u64)(bfbits(v[1])) << 16)
                        | ((u64)(bfbits(v[2])) << 32)
                        | ((u64)(bfbits(v[3])) << 48);
                dst[(size_t)(t*GCOLS + col)*16 + rt*4 + kgrp] = pkk;
            }
        }
        __syncthreads();
    }
}

// ---------------- Phase 2: persistent recurrence, dual-protocol exchange ----------------
__global__ __launch_bounds__(NT, 1)
void lstm_main(const float* __restrict__ Wh,
               const float* __restrict__ Wfc,
               const float* __restrict__ bfc,
               float* __restrict__ out,        // [64] head + [64*512] h (fp32)
               u64* __restrict__ fastH,        // [2][NB][NPAIR] tagged pairs (sc0)
               u64* __restrict__ slowH,        // [2][NB][NPAIR] tagged pairs (agent)
               const u64* __restrict__ xg64)   // xg[t][col][batchquad]
{
    const int tid  = threadIdx.x;
    const int lane = tid & 63;
    const int wv   = tid >> 6;        // 0..3
    const int g    = blockIdx.x & 7;  // domain (-> one XCD under round-robin)
    const int ug   = blockIdx.x >> 3; // unit group 0..7 (64 units each)
    const int kgrp = lane >> 4;
    const int cl   = lane & 15;

    __shared__ __align__(16) bf16_t h_lds[16][HH];    // rows 8..15 stay zero
    __shared__ __align__(16) float  P_lds[16][NCOLP];

    // zero h_lds (h_{-1}=0)
    for (int i = tid; i < 16*HH/2; i += NT) ((u32*)h_lds)[i] = 0u;

    // ---- Wh fragments: 4 n-tiles per wave (256 local cols per block) ----
    bf16x8 whf[16][4];
    #pragma unroll
    for (int nt = 0; nt < 4; ++nt) {
        int gc = ug*256 + wv*64 + nt*16 + cl;       // global gate-col
        int wrow = (gc & 3)*HH + (gc >> 2);
        const float* wr = Wh + (size_t)wrow*HH;
        #pragma unroll
        for (int kt = 0; kt < 16; ++kt) {
            const float4* p = (const float4*)(wr + kt*32 + kgrp*8);
            whf[kt][nt] = cvt8(p[0], p[1]);
        }
    }

    // thread roles for poll/act: batch sb (0..7), chunk sc (0..31)
    const int sb = tid >> 5, sc = tid & 31;
    const int swz = sb << 3;

    // xg addressing: quad m covers batches 4m..4m+3; local rows kgrp*4+r
    const int m = 2*g + (kgrp & 1);
    int gc[4];
    #pragma unroll
    for (int nt = 0; nt < 4; ++nt) gc[nt] = ug*256 + wv*64 + nt*16 + cl;

    u64 xgc[4], xgn[4];
    #pragma unroll
    for (int nt = 0; nt < 4; ++nt) xgc[nt] = xg64[(size_t)gc[nt]*16 + m];

    float c0 = 0.f, c1 = 0.f;
    __syncthreads();

    for (int t = 0; t < TB; ++t) {
        // ---- poll tagged h_{t-1} (8 pairs from one producer), stage to LDS ----
        if (t > 0) {
            size_t off = ((size_t)((t & 1) ^ 1))*NB*NPAIR
                       + (size_t)(g*DB + sb)*NPAIR + sc*8;
            u64 pk[4];
            poll8_dual(fastH + off, slowH + off, (u32)t, pk);
            #pragma unroll
            for (int k = 0; k < 4; ++k) {
                int e = sc*16 + 4*k;
                int phys = ((e & ~7) ^ swz) | (e & 7);
                *(u64*)&h_lds[sb][phys] = pk[k];
            }
        }

        // ---- prefetch xg(t+1): sequential, one full step of slack ----
        if (t + 1 < TB) {
            #pragma unroll
            for (int nt = 0; nt < 4; ++nt)
                xgn[nt] = xg64[(size_t)((t + 1)*GCOLS + gc[nt])*16 + m];
        }
        __syncthreads();   // B1: h_lds visible

        // ---- recurrent MFMAs, acc seeded from xg (bias pre-folded) ----
        f32x4 acc[4];
        #pragma unroll
        for (int nt = 0; nt < 4; ++nt) acc[nt] = cvtxg(xgc[nt]);
        if (t > 0) {
            #pragma unroll
            for (int kt = 0; kt < 16; ++kt) {
                bf16x8 a = *(const bf16x8*)&h_lds[cl][(kt*32 + kgrp*8) ^ ((cl & 7) << 3)];
                #pragma unroll
                for (int nt = 0; nt < 4; ++nt)
                    acc[nt] = __builtin_amdgcn_mfma_f32_16x16x32_bf16(a, whf[kt][nt], acc[nt], 0, 0, 0);
            }
        }

        // ---- preactivations: row = kgrp*4+r (local batch), col = local gate-col ----
        #pragma unroll
        for (int nt = 0; nt < 4; ++nt)
            #pragma unroll
            for (int r = 0; r < 4; ++r)
                P_lds[kgrp*4 + r][wv*64 + nt*16 + cl] = acc[nt][r];
        __syncthreads();   // B2: P visible

        // ---- activations: thread owns (batch sb, units 2*sc, 2*sc+1) ----
        {
            float4 g0 = *(const float4*)&P_lds[sb][sc*8];
            float4 g1 = *(const float4*)&P_lds[sb][sc*8 + 4];
            float r0 = sigf(g0.x), f0 = sigf(g0.y), z0 = tanhfast(g0.z), o0 = sigf(g0.w);
            float r1 = sigf(g1.x), f1 = sigf(g1.y), z1 = tanhfast(g1.z), o1 = sigf(g1.w);
            c0 = f0*c0 + r0*z0;
            c1 = f1*c1 + r1*z1;
            float h0 = o0*tanhfast(c0);
            float h1 = o1*tanhfast(c1);
            if (t == TB - 1) {
                float2 hw = { h0, h1 };
                *(float2*)&out[64 + (size_t)(g*DB + sb)*HH + ug*64 + 2*sc] = hw;
            }
            // dual publish: tagged u64, fast (sc0) + slow (agent atomic)
            u64 v = (((u64)(u32)(t + 1)) << 32)
                  | (u64)(bfbits(h0) | (bfbits(h1) << 16));
            size_t di = ((size_t)(t & 1))*NB*NPAIR
                      + (size_t)(g*DB + sb)*NPAIR + ug*32 + sc;
            asm volatile("global_store_dwordx2 %0, %1, off sc0"
                         :: "v"((u64)(fastH + di)), "v"(v) : "memory");
            __hip_atomic_store(slowH + di, v, __ATOMIC_RELAXED, __HIP_MEMORY_SCOPE_AGENT);
        }
        #pragma unroll
        for (int nt = 0; nt < 4; ++nt) xgc[nt] = xgn[nt];
        // no end-of-step barrier, no flag, no fence
    }

    // ---- final FC head: block ug==0 of each domain ----
    if (ug == 0) {
        size_t off = ((size_t)((TB - 1) & 1))*NB*NPAIR
                   + (size_t)(g*DB + sb)*NPAIR + sc*8;
        u64 pk[4];
        poll8_dual(fastH + off, slowH + off, (u32)TB, pk);
        float s = 0.f;
        const float4* wp = (const float4*)(Wfc + sc*16);
        #pragma unroll
        for (int k = 0; k < 4; ++k) {
            float4 w = wp[k];
            u64 p = pk[k];
            s += __uint_as_float((u32)( p        & 0xFFFFu) << 16) * w.x;
            s += __uint_as_float((u32)((p >> 16) & 0xFFFFu) << 16) * w.y;
            s += __uint_as_float((u32)((p >> 32) & 0xFFFFu) << 16) * w.z;
            s += __uint_as_float((u32)((p >> 48) & 0xFFFFu) << 16) * w.w;
        }
        __syncthreads();   // all act-phase P_lds reads done
        P_lds[sb][sc] = s;
        __syncthreads();
        if (tid < 8) {
            float acc = 0.f;
            #pragma unroll
            for (int q = 0; q < 32; ++q) acc += P_lds[tid][q];
            out[g*DB + tid] = sigf(acc + bfc[0]);
        }
    }
}

extern "C" void kernel_launch(void* const* d_in, const int* in_sizes, int n_in,
                              void* d_out, int out_size, void* d_ws, size_t ws_size,
                              hipStream_t stream) {
    (void)in_sizes; (void)n_in; (void)out_size; (void)ws_size;
    const int*   words = (const int*)d_in[0];
    const float* emb   = (const float*)d_in[1];
    const float* Wi    = (const float*)d_in[2];
    const float* bi    = (const float*)d_in[3];
    const float* Wh    = (const float*)d_in[4];
    const float* bh    = (const float*)d_in[5];
    const float* Wfc   = (const float*)d_in[6];
    const float* bfc   = (const float*)d_in[7];
    float* out = (float*)d_out;

    u64* fastH  = (u64*)d_ws;
    u64* slowH  = (u64*)((char*)d_ws + SLOWOFF);
    bf16_t* xgT = (bf16_t*)((char*)d_ws + XGOFF);

    // zero both tag buffers every launch (tag 0 matches no step)
    hipMemsetAsync(d_ws, 0, 2*SLOWOFF, stream);

    xg_prepass<<<dim3(256), dim3(256), 0, stream>>>(words, emb, Wi, bi, bh, xgT);
    lstm_main<<<dim3(ND*NBLK), dim3(NT), 0, stream>>>(Wh, Wfc, bfc, out,
                                                      fastH, slowH, (const u64*)xgT);
}